// Round 1
// 61.357 us; speedup vs baseline: 1.0169x; 1.0169x over previous
//
#include <hip/hip_runtime.h>

// SeparationLoss: landmarks [B=1024, N=256, D=2] fp32 -> scalar fp32
//   sum_b sum_{i<j} d2 * exp(-d2/25),  d2 = ||x_i - x_j||^2
//
// v2 vs the 61.8us baseline:
//  * FIX overcount: the old loop (j=1; j<=125; j+=4) covered offsets 1..128
//    at FULL weight (j=125 group reads row[125..128]) plus the extra 0.5x
//    j=128 term -> distance-128 pairs counted 3x per unordered pair.
//    Predicted excess ~8e5 matches the measured absmax 1.05e6.
//    Now: offsets 1..127 full weight + 128 half weight, exactly.
//  * Coordinates pre-scaled by g = sqrt(log2(e)/25) at LDS fill:
//    u = |Pi-Pj|^2 = d2*log2e/25, term = u*exp2(-u)/k. Inner loop is
//    sub,sub,mul,fma,exp2(-u) (neg folds into VOP3 modifier), fmac
//    = 5 VALU + 1 exp per pair (was 6 + exp). Final scale 25*ln2 in reduce.
//  * Each batch split across 2 blocks (offsets 1..64 | 65..128): 2048
//    blocks, 64 pair-ops/thread, launch_bounds(256,8) keeps VGPR<=64 ->
//    8 blocks/CU = 32 waves/CU (was 16) to hide exp + LDS latency.
//
// Circular pairing: thread i pairs with (i+j) mod 256; points duplicated in
// LDS so (i+j) needs no modulo -> imm-offset ds_read_b64, 2-way bank alias
// (free, m136). 4 accumulators break the strict-FP serial add chain.

#define N_PTS 256
#define SCALE_G 0.2402244818f   // sqrt(log2(e)/25)
#define INV_K   17.328679514f   // 25*ln(2) = 1/(log2(e)/25)

__device__ __forceinline__ float fast_exp2(float x) {
#if __has_builtin(__builtin_amdgcn_exp2f)
    return __builtin_amdgcn_exp2f(x);
#else
    return exp2f(x);
#endif
}

#define PAIR(Q, ACC) do { \
    float dx_ = xi - (Q).x, dy_ = yi - (Q).y; \
    float u_ = dx_ * dx_ + dy_ * dy_; \
    ACC += u_ * fast_exp2(-u_); \
} while (0)

__global__ __launch_bounds__(256, 8) void sep_main(
    const float* __restrict__ lm, float* __restrict__ partial) {
    __shared__ float2 pts[2 * N_PTS];
    const int blk = blockIdx.x;
    const int b = blk >> 1;   // batch index
    const int hi = blk & 1;   // 0: offsets 1..64, 1: offsets 65..128
    const int t = threadIdx.x;

    const float2* src = (const float2*)(lm + (size_t)b * N_PTS * 2);
    float2 p = src[t];        // coalesced 8B/lane
    p.x *= SCALE_G;
    p.y *= SCALE_G;
    pts[t] = p;
    pts[t + N_PTS] = p;       // duplicate: kills the modulo
    __syncthreads();

    const float xi = p.x, yi = p.y;
    const float2* row = &pts[t];

    float s0 = 0.f, s1 = 0.f, s2 = 0.f, s3 = 0.f;
    if (hi == 0) {
        // offsets 1..64: 16 groups of 4
#pragma unroll 4
        for (int j = 1; j <= 61; j += 4) {
            float2 q0 = row[j];
            float2 q1 = row[j + 1];
            float2 q2 = row[j + 2];
            float2 q3 = row[j + 3];
            PAIR(q0, s0); PAIR(q1, s1); PAIR(q2, s2); PAIR(q3, s3);
        }
    } else {
        // offsets 65..124: 15 groups of 4
#pragma unroll 4
        for (int j = 65; j <= 121; j += 4) {
            float2 q0 = row[j];
            float2 q1 = row[j + 1];
            float2 q2 = row[j + 2];
            float2 q3 = row[j + 3];
            PAIR(q0, s0); PAIR(q1, s1); PAIR(q2, s2); PAIR(q3, s3);
        }
        // singles 125..127 full weight, 128 half weight (pair hit twice)
        float2 q0 = row[125];
        float2 q1 = row[126];
        float2 q2 = row[127];
        float2 q3 = row[128];
        PAIR(q0, s0); PAIR(q1, s1); PAIR(q2, s2);
        {
            float dx_ = xi - q3.x, dy_ = yi - q3.y;
            float u_ = dx_ * dx_ + dy_ * dy_;
            s3 += 0.5f * u_ * fast_exp2(-u_);
        }
    }

    float s = (s0 + s1) + (s2 + s3);

    // wave butterfly reduce (64 lanes)
    for (int off = 32; off > 0; off >>= 1) s += __shfl_down(s, off, 64);

    __shared__ float wsum[4];
    if ((t & 63) == 0) wsum[t >> 6] = s;
    __syncthreads();
    if (t == 0) partial[blk] = (wsum[0] + wsum[1]) + (wsum[2] + wsum[3]);
}

__global__ __launch_bounds__(256) void sep_reduce(
    const float* __restrict__ partial, float* __restrict__ out, int n4) {
    const int t = threadIdx.x;
    const float4* p4 = (const float4*)partial;
    float s = 0.f;
    for (int i = t; i < n4; i += 256) {
        float4 v = p4[i];
        s += (v.x + v.y) + (v.z + v.w);
    }
    for (int off = 32; off > 0; off >>= 1) s += __shfl_down(s, off, 64);
    __shared__ float wsum[4];
    if ((t & 63) == 0) wsum[t >> 6] = s;
    __syncthreads();
    if (t == 0)
        out[0] = ((wsum[0] + wsum[1]) + (wsum[2] + wsum[3])) * INV_K;
}

extern "C" void kernel_launch(void* const* d_in, const int* in_sizes, int n_in,
                              void* d_out, int out_size, void* d_ws, size_t ws_size,
                              hipStream_t stream) {
    const float* landmarks = (const float*)d_in[0];
    float* out = (float*)d_out;
    float* partial = (float*)d_ws;            // 2048 floats = 8 KB

    const int B = in_sizes[0] / (N_PTS * 2);  // 1024

    sep_main<<<2 * B, N_PTS, 0, stream>>>(landmarks, partial);
    sep_reduce<<<1, N_PTS, 0, stream>>>(partial, out, (2 * B) / 4);
}